// Round 6
// baseline (5683.182 us; speedup 1.0000x reference)
//
#include <hip/hip_runtime.h>
#include <hip/hip_fp16.h>

#define NN 100000
#define NE 1600000
#define HD 128
#define HD2 256

// binned scatter params
#define NBK 512
#define RPB 196      // rows per bucket; 512*196 = 100352 >= NN
#define CH  4096     // edges per binscatter block
#define CAP 4096     // staging capacity per bucket (17-sigma above mean 3136)

typedef unsigned int u32;
typedef unsigned short u16;
typedef _Float16 half8 __attribute__((ext_vector_type(8)));
typedef float floatx4 __attribute__((ext_vector_type(4)));

static inline int cdiv(int a, int b){ return (a + b - 1) / b; }

// ---- split-fp16 packing: x ~= h + l * 2^-12, l pre-scaled by 4096 ----
__device__ __forceinline__ u32 split_pack(float v){
  __half h;
  if(fabsf(v) < 6.103515625e-05f) h = __ushort_as_half((u16)0);
  else h = __float2half_rn(v);
  float hf = __half2float(h);
  __half l = __float2half_rn((v - hf) * 4096.0f);
  return (u32)__half_as_ushort(h) | ((u32)__half_as_ushort(l) << 16);
}

// ---------------- utility kernels ----------------
__global__ void k_zero_f(float* __restrict__ p, int n){
  int i = blockIdx.x * 256 + threadIdx.x;
  if(i < n) p[i] = 0.f;
}

// bucket cursor init: staging region for bucket b starts at b*CAP
__global__ void k_init_bcap(int* __restrict__ bcur){
  int i = blockIdx.x * 256 + threadIdx.x;
  if(i < 2 * NBK) bcur[i] = (i & (NBK - 1)) * CAP;
}

// pass B: LDS-binned scatter into fixed-capacity bucket staging (burst writes)
__global__ void k_binscatter(const int* __restrict__ r0a, const int* __restrict__ c0a,
                             const float* __restrict__ v0a,
                             const int* __restrict__ r1a, const int* __restrict__ c1a,
                             const float* __restrict__ v1a,
                             int* __restrict__ bcur,
                             u32* __restrict__ sr0, uint2* __restrict__ sv0,
                             u32* __restrict__ sr1, uint2* __restrict__ sv1){
  __shared__ int cnt[NBK];
  __shared__ int bstart[NBK];
  __shared__ int gbase[NBK];
  __shared__ int sh[256];
  __shared__ u32 srow[CH];
  __shared__ uint2 scvs[CH];
  int z = blockIdx.y;
  const int* rows = z ? r1a : r0a;
  const int* cols = z ? c1a : c0a;
  const float* vals = z ? v1a : v0a;
  int* cur = bcur + z * NBK;
  u32* osr = z ? sr1 : sr0;
  uint2* osv = z ? sv1 : sv0;
  int t = threadIdx.x;
  for(int i = t; i < NBK; i += 256) cnt[i] = 0;
  __syncthreads();
  int e0 = blockIdx.x * CH;
  int total = NE - e0; if(total > CH) total = CH;
  int r_[16], c_[16], b_[16], k_[16]; float v_[16];
  #pragma unroll
  for(int k = 0; k < 16; k++){
    int e = e0 + t + k * 256;
    b_[k] = -1;
    if(e < NE){
      r_[k] = rows[e]; c_[k] = cols[e]; v_[k] = vals[e];
      b_[k] = r_[k] / RPB;
      k_[k] = atomicAdd(&cnt[b_[k]], 1);
    }
  }
  __syncthreads();
  // exclusive scan of cnt[512] with 256 threads (2 elems/thread)
  int v0 = cnt[2 * t], v1 = cnt[2 * t + 1];
  int s2 = v0 + v1;
  sh[t] = s2;
  __syncthreads();
  for(int d = 1; d < 256; d <<= 1){
    int tv = (t >= d) ? sh[t - d] : 0;
    __syncthreads();
    sh[t] += tv;
    __syncthreads();
  }
  int excl = sh[t] - s2;
  bstart[2 * t] = excl;
  bstart[2 * t + 1] = excl + v0;
  __syncthreads();
  // stage into LDS sorted-by-bucket
  #pragma unroll
  for(int k = 0; k < 16; k++){
    if(b_[k] >= 0){
      int slot = bstart[b_[k]] + k_[k];
      srow[slot] = (u32)r_[k];
      scvs[slot] = make_uint2((u32)c_[k], __float_as_uint(v_[k]));
    }
  }
  // reserve staging space per bucket (one atomic per non-empty bucket)
  for(int b = t; b < NBK; b += 256){
    int c = cnt[b];
    if(c > 0) gbase[b] = atomicAdd(&cur[b], c);
  }
  __syncthreads();
  // burst write-out: consecutive i -> same bucket -> contiguous dest
  for(int i = t; i < total; i += 256){
    u32 r = srow[i];
    int b = (int)r / RPB;
    int dest = gbase[b] + (i - bstart[b]);
    osr[dest] = r;
    osv[dest] = scvs[i];
  }
}

// bucket totals -> global bucket bases (exclusive scan over 512), + rowptr[NN]=NE
__global__ void k_bucket_scan(const int* __restrict__ bcur, int* __restrict__ bbase,
                              int* __restrict__ c1ptr, int* __restrict__ c2ptr){
  __shared__ int sh[256];
  int z = blockIdx.x;
  const int* cur = bcur + z * NBK;
  int* bb = bbase + z * NBK;
  int t = threadIdx.x;
  int v0 = cur[2 * t]     - (2 * t) * CAP;
  int v1 = cur[2 * t + 1] - (2 * t + 1) * CAP;
  int s2 = v0 + v1;
  sh[t] = s2;
  __syncthreads();
  for(int d = 1; d < 256; d <<= 1){
    int tv = (t >= d) ? sh[t - d] : 0;
    __syncthreads();
    sh[t] += tv;
    __syncthreads();
  }
  int excl = sh[t] - s2;
  bb[2 * t] = excl;
  bb[2 * t + 1] = excl + v0;
  if(t == 0){
    int* rp = z ? c2ptr : c1ptr;
    rp[NN] = NE;
  }
}

// pass C: per-bucket — LDS row-histogram + local scan -> rowptr, then CSR placement
__global__ void k_bucket_place(const int* __restrict__ bcur, const int* __restrict__ bbase,
                               const u32* __restrict__ sr0, const uint2* __restrict__ sv0,
                               const u32* __restrict__ sr1, const uint2* __restrict__ sv1,
                               int* __restrict__ c1ptr, int* __restrict__ c2ptr,
                               uint2* __restrict__ e0, uint2* __restrict__ e1){
  __shared__ int hist[RPB];
  __shared__ int cur[RPB];
  __shared__ int sh[256];
  __shared__ u32 srows[CAP];
  int z = blockIdx.y;
  int b = blockIdx.x;
  int r0 = b * RPB;
  if(r0 >= NN) return;
  int rend = r0 + RPB; if(rend > NN) rend = NN;
  int nr = rend - r0;
  const u32* sr = z ? sr1 : sr0;
  const uint2* sv = z ? sv1 : sv0;
  int* rp = z ? c2ptr : c1ptr;
  uint2* ecv = z ? e1 : e0;
  int cnt = bcur[z * NBK + b] - b * CAP;
  int base = bbase[z * NBK + b];
  int g = b * CAP;
  int t = threadIdx.x;
  for(int r = t; r < nr; r += 256) hist[r] = 0;
  __syncthreads();
  for(int i = t; i < cnt; i += 256){
    u32 r = sr[g + i];
    srows[i] = r;
    atomicAdd(&hist[(int)r - r0], 1);
  }
  __syncthreads();
  int v = (t < nr) ? hist[t] : 0;
  sh[t] = v;
  __syncthreads();
  for(int d = 1; d < 256; d <<= 1){
    int tv = (t >= d) ? sh[t - d] : 0;
    __syncthreads();
    sh[t] += tv;
    __syncthreads();
  }
  int excl = sh[t] - v;
  if(t < nr){
    rp[r0 + t] = base + excl;
    cur[t] = base + excl;
  }
  __syncthreads();
  for(int i = t; i < cnt; i += 256){
    int r = (int)srows[i] - r0;
    int p = atomicAdd(&cur[r], 1);
    ecv[p] = sv[g + i];
  }
}

// weight pre-split: W is [K][N] row-major fp32; out is packed [N][K] (transposed)
__global__ void k_splitw(const float* __restrict__ W, u32* __restrict__ out,
                         int K, int N, int total){
  int idx = blockIdx.x * 256 + threadIdx.x;
  if(idx < total){
    int n = idx / K, k = idx - n * K;
    out[idx] = split_pack(W[(size_t)k * N + n]);
  }
}

// ---------------- SpMM body: one wave per node; relu (+ optional l2norm) ----------------
template<bool NORM>
__device__ __forceinline__ void dev_spmm(int vb, const int* __restrict__ rowptr,
                                         const uint2* __restrict__ ecv,
                                         const float* __restrict__ X,
                                         u32* __restrict__ outpk){
  int node = (vb << 2) + ((int)threadIdx.x >> 6);
  int lane = threadIdx.x & 63;
  if(node >= NN) return;
  int s = rowptr[node], e = rowptr[node + 1];
  float ax = 0.f, ay = 0.f, bx = 0.f, by = 0.f;
  int i = s;
  for(; i + 15 < e; i += 16){
    uint2 ee[16]; float2 xx[16];
    #pragma unroll
    for(int j = 0; j < 16; j++) ee[j] = ecv[i + j];
    #pragma unroll
    for(int j = 0; j < 16; j++) xx[j] = *(const float2*)(X + (size_t)ee[j].x * HD + lane * 2);
    #pragma unroll
    for(int j = 0; j < 16; j += 4){
      ax += __uint_as_float(ee[j].y)   * xx[j].x   + __uint_as_float(ee[j+1].y) * xx[j+1].x;
      ay += __uint_as_float(ee[j].y)   * xx[j].y   + __uint_as_float(ee[j+1].y) * xx[j+1].y;
      bx += __uint_as_float(ee[j+2].y) * xx[j+2].x + __uint_as_float(ee[j+3].y) * xx[j+3].x;
      by += __uint_as_float(ee[j+2].y) * xx[j+2].y + __uint_as_float(ee[j+3].y) * xx[j+3].y;
    }
  }
  for(; i + 3 < e; i += 4){
    uint2 f0 = ecv[i], f1 = ecv[i+1], f2 = ecv[i+2], f3 = ecv[i+3];
    float2 x0 = *(const float2*)(X + (size_t)f0.x * HD + lane * 2);
    float2 x1 = *(const float2*)(X + (size_t)f1.x * HD + lane * 2);
    float2 x2 = *(const float2*)(X + (size_t)f2.x * HD + lane * 2);
    float2 x3 = *(const float2*)(X + (size_t)f3.x * HD + lane * 2);
    ax += __uint_as_float(f0.y) * x0.x + __uint_as_float(f1.y) * x1.x;
    ay += __uint_as_float(f0.y) * x0.y + __uint_as_float(f1.y) * x1.y;
    bx += __uint_as_float(f2.y) * x2.x + __uint_as_float(f3.y) * x3.x;
    by += __uint_as_float(f2.y) * x2.y + __uint_as_float(f3.y) * x3.y;
  }
  for(; i < e; i++){
    uint2 f0 = ecv[i];
    float2 xv = *(const float2*)(X + (size_t)f0.x * HD + lane * 2);
    ax += __uint_as_float(f0.y) * xv.x;
    ay += __uint_as_float(f0.y) * xv.y;
  }
  ax += bx; ay += by;
  ax = fmaxf(ax, 0.f);
  ay = fmaxf(ay, 0.f);
  if(NORM){
    float ss = ax * ax + ay * ay;
    #pragma unroll
    for(int o = 32; o >= 1; o >>= 1) ss += __shfl_xor(ss, o, 64);
    float scale = 1.f / fmaxf(sqrtf(ss), 1e-12f);
    ax *= scale; ay *= scale;
  }
  *(uint2*)(outpk + (size_t)node * HD + lane * 2) = make_uint2(split_pack(ax), split_pack(ay));
}

template<bool NORM>
__global__ void k_spmm(const int* __restrict__ rowptr, const uint2* __restrict__ ecv,
                       const float* __restrict__ X, u32* __restrict__ outpk){
  dev_spmm<NORM>(blockIdx.x, rowptr, ecv, X, outpk);
}

// ---------------- split-fp16 MFMA GEMM body (round-6-proven, XCD-paired col-tiles) ----
// 1-D virtual block id d -> (row-tile rt, col-tile ct): all NYC col-tiles of a
// row-panel land on the SAME XCD (d%8 equal) -> A panel L2-reuse.
// MODE 0: Yout = A@B (fp32). MODE 1: Hout = pack(relu(A@B+bias)).
// MODE 2: score[m] += sum_n relu(A@B+bias)[m][n]*m3[n].
// MODE 3: fused — ct==0: mode0 -> Yout [M][HD]; ct in {1,2}: mode1 with Bt1 -> Hout.
template<int MODE>
__device__ __forceinline__ void dev_gemm(int d,
                            const u32* __restrict__ Apk, const u32* __restrict__ Btpk,
                            const u32* __restrict__ Bt1pk,
                            const float* __restrict__ bias, float* __restrict__ Yout,
                            u32* __restrict__ Hout, const float* __restrict__ m3,
                            float* __restrict__ score, int M, int K, int N,
                            u16* As_h, u16* As_l, u16* Bs_h, u16* Bs_l){
  constexpr int NYC = (MODE == 0) ? 1 : ((MODE == 3) ? 3 : 2);
  const int grp = d / (8 * NYC);
  const int rem = d - grp * 8 * NYC;
  const int rt = grp * 8 + (rem & 7);
  const int ct = rem >> 3;
  const int nrt = (M + 127) >> 7;
  if(rt >= nrt) return;
  const int tid = threadIdx.x;
  const int lane = tid & 63, wid = tid >> 6;
  const int lm = lane & 15, lg = lane >> 4;
  const int mq = (wid & 1) * 64, nq = (wid >> 1) * 64;
  const int m0 = rt * 128;
  int n0 = ct * 128;
  const u32* Bt = Btpk;
  bool m0path = true;
  if(MODE == 3){
    m0path = (ct == 0);
    if(m0path){ n0 = 0; }
    else      { n0 = (ct - 1) * 128; Bt = Bt1pk; }
  }

  floatx4 accA[4][4], accB[4][4];
  #pragma unroll
  for(int i = 0; i < 4; i++)
    #pragma unroll
    for(int j = 0; j < 4; j++){
      accA[i][j] = (floatx4){0.f, 0.f, 0.f, 0.f};
      accB[i][j] = (floatx4){0.f, 0.f, 0.f, 0.f};
    }

  for(int k0 = 0; k0 < K; k0 += 32){
    uint4 av[4], bv[4];
    #pragma unroll
    for(int j = 0; j < 4; j++){
      int li = tid + j * 256;
      int row = li >> 3, kc = (li & 7) * 4;
      int ar = m0 + row; if(ar >= M) ar = M - 1;
      av[j] = *(const uint4*)(Apk + (size_t)ar * K + k0 + kc);
      bv[j] = *(const uint4*)(Bt + (size_t)(n0 + row) * K + k0 + kc);
    }
    if(k0) __syncthreads();
    #pragma unroll
    for(int j = 0; j < 4; j++){
      int li = tid + j * 256;
      int row = li >> 3, kc = (li & 7) * 4;
      int base = row * 40 + kc;
      ushort4 h, l;
      h.x = (u16)(av[j].x & 0xffff); l.x = (u16)(av[j].x >> 16);
      h.y = (u16)(av[j].y & 0xffff); l.y = (u16)(av[j].y >> 16);
      h.z = (u16)(av[j].z & 0xffff); l.z = (u16)(av[j].z >> 16);
      h.w = (u16)(av[j].w & 0xffff); l.w = (u16)(av[j].w >> 16);
      *(ushort4*)&As_h[base] = h;
      *(ushort4*)&As_l[base] = l;
      h.x = (u16)(bv[j].x & 0xffff); l.x = (u16)(bv[j].x >> 16);
      h.y = (u16)(bv[j].y & 0xffff); l.y = (u16)(bv[j].y >> 16);
      h.z = (u16)(bv[j].z & 0xffff); l.z = (u16)(bv[j].z >> 16);
      h.w = (u16)(bv[j].w & 0xffff); l.w = (u16)(bv[j].w >> 16);
      *(ushort4*)&Bs_h[base] = h;
      *(ushort4*)&Bs_l[base] = l;
    }
    __syncthreads();

    half8 fa_h[4], fa_l[4], fb_h[4], fb_l[4];
    #pragma unroll
    for(int s = 0; s < 4; s++){
      int ra = (mq + s * 16 + lm) * 40 + lg * 8;
      fa_h[s] = *(const half8*)&As_h[ra];
      fa_l[s] = *(const half8*)&As_l[ra];
      int rb = (nq + s * 16 + lm) * 40 + lg * 8;
      fb_h[s] = *(const half8*)&Bs_h[rb];
      fb_l[s] = *(const half8*)&Bs_l[rb];
    }
    #pragma unroll
    for(int i = 0; i < 4; i++)
      #pragma unroll
      for(int j = 0; j < 4; j++){
        accA[i][j] = __builtin_amdgcn_mfma_f32_16x16x32_f16(fa_h[i], fb_h[j], accA[i][j], 0, 0, 0);
        accB[i][j] = __builtin_amdgcn_mfma_f32_16x16x32_f16(fa_h[i], fb_l[j], accB[i][j], 0, 0, 0);
        accB[i][j] = __builtin_amdgcn_mfma_f32_16x16x32_f16(fa_l[i], fb_h[j], accB[i][j], 0, 0, 0);
      }
  }

  const float inv4096 = 1.f / 4096.f;
  if(MODE == 0 || (MODE == 3 && m0path)){
    int ldy = (MODE == 3) ? HD : N;
    #pragma unroll
    for(int i = 0; i < 4; i++)
      #pragma unroll
      for(int r = 0; r < 4; r++){
        int m = m0 + mq + i * 16 + lg * 4 + r;
        if(m < M){
          #pragma unroll
          for(int j = 0; j < 4; j++){
            int c = n0 + nq + j * 16 + lm;
            Yout[(size_t)m * ldy + c] = accA[i][j][r] + accB[i][j][r] * inv4096;
          }
        }
      }
  } else if(MODE == 1 || MODE == 3){
    int ldh = (MODE == 3) ? HD2 : N;
    #pragma unroll
    for(int i = 0; i < 4; i++)
      #pragma unroll
      for(int r = 0; r < 4; r++){
        int m = m0 + mq + i * 16 + lg * 4 + r;
        if(m < M){
          #pragma unroll
          for(int j = 0; j < 4; j++){
            int c = n0 + nq + j * 16 + lm;
            float v = fmaxf(accA[i][j][r] + accB[i][j][r] * inv4096 + bias[c], 0.f);
            Hout[(size_t)m * ldh + c] = split_pack(v);
          }
        }
      }
  } else {
    #pragma unroll
    for(int i = 0; i < 4; i++)
      #pragma unroll
      for(int r = 0; r < 4; r++){
        float s = 0.f;
        #pragma unroll
        for(int j = 0; j < 4; j++){
          int c = n0 + nq + j * 16 + lm;
          float v = fmaxf(accA[i][j][r] + accB[i][j][r] * inv4096 + bias[c], 0.f);
          s = fmaf(v, m3[c], s);
        }
        s += __shfl_xor(s, 1, 64);
        s += __shfl_xor(s, 2, 64);
        s += __shfl_xor(s, 4, 64);
        s += __shfl_xor(s, 8, 64);
        int m = m0 + mq + i * 16 + lg * 4 + r;
        if(lm == 0 && m < M) atomicAdd(&score[m], s);
      }
  }
}

template<int MODE>
__launch_bounds__(256, 2)
__global__ void k_mfma_gemm(const u32* __restrict__ Apk, const u32* __restrict__ Btpk,
                            const u32* __restrict__ Bt1pk,
                            const float* __restrict__ bias, float* __restrict__ Yout,
                            u32* __restrict__ Hout, const float* __restrict__ m3,
                            float* __restrict__ score, int M, int K, int N){
  __shared__ u16 As_h[128 * 40], As_l[128 * 40];
  __shared__ u16 Bs_h[128 * 40], Bs_l[128 * 40];
  dev_gemm<MODE>(blockIdx.x, Apk, Btpk, Bt1pk, bias, Yout, Hout, m3, score,
                 M, K, N, As_h, As_l, Bs_h, Bs_l);
}

// ---------------- paired dispatch: mode2 GEMM blocks + independent SpMM blocks ----------
// mode2(i) (reads h1pk, adds sc) and spmm(i) (reads y/ecv, writes xpk) are mutually
// independent — co-scheduling them lets MFMA-bound and gather-bound waves overlap.
template<bool NORM>
__launch_bounds__(256, 2)
__global__ void k_pair(const u32* __restrict__ Apk, const u32* __restrict__ Btpk,
                       const float* __restrict__ bias, const float* __restrict__ m3,
                       float* __restrict__ score, int gb,
                       const int* __restrict__ rowptr, const uint2* __restrict__ ecv,
                       const float* __restrict__ X, u32* __restrict__ outpk){
  __shared__ u16 As_h[128 * 40], As_l[128 * 40];
  __shared__ u16 Bs_h[128 * 40], Bs_l[128 * 40];
  if((int)blockIdx.x < gb){
    dev_gemm<2>(blockIdx.x, Apk, Btpk, (const u32*)nullptr, bias, (float*)nullptr,
                (u32*)nullptr, m3, score, NN, HD2, HD2, As_h, As_l, Bs_h, Bs_l);
  } else {
    dev_spmm<NORM>((int)blockIdx.x - gb, rowptr, ecv, X, outpk);
  }
}

__global__ void k_final(const float* __restrict__ sc, const float* __restrict__ b3,
                        float* __restrict__ out){
  int i = blockIdx.x * 256 + threadIdx.x;
  if(i < NN){
    float b = 9.f * b3[0];
    out[i] = (sc[i] + b) * (sc[NN + i] + b);
  }
}

// ---------------- launcher ----------------
extern "C" void kernel_launch(void* const* d_in, const int* in_sizes, int n_in,
                              void* d_out, int out_size, void* d_ws, size_t ws_size,
                              hipStream_t stream){
  const int*   a1r = (const int*)d_in[0];
  const int*   a1c = (const int*)d_in[1];
  const float* a1v = (const float*)d_in[2];
  const int*   a2r = (const int*)d_in[3];
  const int*   a2c = (const int*)d_in[4];
  const float* a2v = (const float*)d_in[5];
  const float* w1  = (const float*)d_in[6];
  const float* w[8];
  for(int i = 0; i < 8; i++) w[i] = (const float*)d_in[7 + i];
  const float* m1 = (const float*)d_in[15];
  const float* b1 = (const float*)d_in[16];
  const float* m2 = (const float*)d_in[17];
  const float* b2 = (const float*)d_in[18];
  const float* m3 = (const float*)d_in[19];
  const float* b3 = (const float*)d_in[20];
  float* out = (float*)d_out;

  char* base = (char*)d_ws;
  size_t off = 0;
  auto alloc = [&](size_t bytes) -> char* {
    char* r = base + off;
    off += (bytes + 255) & ~(size_t)255;
    return r;
  };
  int*   c1ptr = (int*)  alloc((size_t)(NN + 1) * 4);
  int*   c2ptr = (int*)  alloc((size_t)(NN + 1) * 4);
  uint2* ecv1  = (uint2*)alloc((size_t)NE * 8);
  uint2* ecv2  = (uint2*)alloc((size_t)NE * 8);
  int*   cursor= (int*)  alloc((size_t)2 * NBK * 4);
  int*   bbase = (int*)  alloc((size_t)2 * NBK * 4);
  float* sc    = (float*)alloc((size_t)2 * NN * 4);
  u32*   wtpk[8];
  for(int i = 0; i < 8; i++) wtpk[i] = (u32*)alloc((size_t)HD * HD * 4);
  u32*   m1tpk = (u32*)alloc((size_t)HD2 * HD * 4);
  u32*   m2tpk = (u32*)alloc((size_t)HD2 * HD2 * 4);
  u32*   xpk   = (u32*)alloc((size_t)NN * HD * 4);
  u32*   h1pk  = (u32*)alloc((size_t)NN * HD2 * 4);
  // fused01 tier needs dedicated y (fp32 [NN][HD]); else alias h1pk and run r6 schedule
  size_t need_ded = off + (((size_t)NN * HD * 4 + 255) & ~(size_t)255);
  bool ded_y = (ws_size >= need_ded);
  float* y = ded_y ? (float*)alloc((size_t)NN * HD * 4) : (float*)h1pk;

  // binned-scatter staging aliases h1pk (dead during CSR build): 50.3MB < 102.4MB
  const size_t SZ = (size_t)NBK * CAP;
  char* hb = (char*)h1pk;
  uint2* sv1 = (uint2*)hb;
  u32*   sr1 = (u32*)(hb + SZ * 8);
  uint2* sv2 = (uint2*)(hb + SZ * 12);
  u32*   sr2 = (u32*)(hb + SZ * 20);

  // ---- bucketized CSR build (both adjacencies; no global per-row histogram) ----
  hipLaunchKernelGGL(k_init_bcap, dim3(cdiv(2 * NBK, 256)), dim3(256), 0, stream, cursor);
  hipLaunchKernelGGL(k_binscatter, dim3(cdiv(NE, CH), 2), dim3(256), 0, stream,
                     a1r, a1c, a1v, a2r, a2c, a2v, cursor, sr1, sv1, sr2, sv2);
  hipLaunchKernelGGL(k_bucket_scan, dim3(2), dim3(256), 0, stream, cursor, bbase, c1ptr, c2ptr);
  hipLaunchKernelGGL(k_bucket_place, dim3(NBK, 2), dim3(256), 0, stream,
                     cursor, bbase, sr1, sv1, sr2, sv2, c1ptr, c2ptr, ecv1, ecv2);

  auto splitw = [&](const float* W, u32* o, int K, int N){
    int total = K * N;
    hipLaunchKernelGGL(k_splitw, dim3(cdiv(total, 256)), dim3(256), 0, stream, W, o, K, N, total);
  };
  for(int i = 0; i < 8; i++) splitw(w[i], wtpk[i], HD, HD);
  splitw(m1, m1tpk, HD, HD2);
  splitw(m2, m2tpk, HD2, HD2);
  hipLaunchKernelGGL(k_zero_f, dim3(cdiv(2 * NN, 256)), dim3(256), 0, stream, sc, 2 * NN);

  const int NRT = cdiv(NN, 128);          // 782 row tiles
  const int GP  = cdiv(NRT, 8) * 8;       // 784 padded rows
  const int SPB = cdiv(NN, 4);            // 25000 spmm blocks
  auto mode1 = [&](){
    hipLaunchKernelGGL((k_mfma_gemm<1>), dim3(GP * 2), dim3(256), 0, stream,
                       xpk, m1tpk, (const u32*)nullptr, b1, (float*)nullptr, h1pk,
                       (const float*)nullptr, (float*)nullptr, NN, HD, HD2);
  };
  auto mode2 = [&](float* score){
    hipLaunchKernelGGL((k_mfma_gemm<2>), dim3(GP * 2), dim3(256), 0, stream,
                       h1pk, m2tpk, (const u32*)nullptr, b2, (float*)nullptr, (u32*)nullptr,
                       m3, score, NN, HD2, HD2);
  };
  auto gemm0 = [&](int i){
    hipLaunchKernelGGL((k_mfma_gemm<0>), dim3(GP * 1), dim3(256), 0, stream,
                       xpk, wtpk[i], (const u32*)nullptr, (const float*)nullptr, y, (u32*)nullptr,
                       (const float*)nullptr, (float*)nullptr, NN, HD, HD);
  };
  auto fused01 = [&](int i){
    hipLaunchKernelGGL((k_mfma_gemm<3>), dim3(GP * 3), dim3(256), 0, stream,
                       xpk, wtpk[i], m1tpk, b1, y, h1pk,
                       (const float*)nullptr, (float*)nullptr, NN, HD, 0);
  };
  // paired: mode2(score) || spmm(rp, ecv, X -> xpk)
  auto pair = [&](float* score, const int* rp, const uint2* ecv, const float* X, bool norm){
    if(norm)
      hipLaunchKernelGGL((k_pair<true>),  dim3(GP * 2 + SPB), dim3(256), 0, stream,
                         h1pk, m2tpk, b2, m3, score, GP * 2, rp, ecv, X, xpk);
    else
      hipLaunchKernelGGL((k_pair<false>), dim3(GP * 2 + SPB), dim3(256), 0, stream,
                         h1pk, m2tpk, b2, m3, score, GP * 2, rp, ecv, X, xpk);
  };

  if(ded_y){
    // b0: spmm_w1; 8x [fused01; pair(mode2 || spmm_y)]; mode1;
    // cross pair(mode2(b0) || spmm_w1(b1)); b1: 8x [...]; mode1; mode2
    hipLaunchKernelGGL((k_spmm<true>), dim3(SPB), dim3(256), 0, stream,
                       c1ptr, ecv1, w1, xpk);
    for(int b = 0; b < 2; b++){
      const int* rp = b ? c2ptr : c1ptr;
      const uint2* ecv = b ? ecv2 : ecv1;
      float* score = sc + (size_t)b * NN;
      for(int i = 0; i < 8; i++){
        fused01(i);
        pair(score, rp, ecv, y, i < 7);
      }
      mode1();
      if(b == 0){
        // final mode2 of b0 paired with b1's first spmm (independent)
        pair(score, c2ptr, ecv2, w1, true);
      } else {
        mode2(score);
      }
    }
  } else {
    // r6-proven serial order (y aliases h1pk)
    for(int b = 0; b < 2; b++){
      const int* rp = b ? c2ptr : c1ptr;
      const uint2* ecv = b ? ecv2 : ecv1;
      float* score = sc + (size_t)b * NN;
      hipLaunchKernelGGL((k_spmm<true>), dim3(SPB), dim3(256), 0, stream,
                         rp, ecv, w1, xpk);
      mode1();
      mode2(score);
      for(int i = 0; i < 8; i++){
        gemm0(i);
        if(i < 7)
          hipLaunchKernelGGL((k_spmm<true>),  dim3(SPB), dim3(256), 0, stream,
                             rp, ecv, y, xpk);
        else
          hipLaunchKernelGGL((k_spmm<false>), dim3(SPB), dim3(256), 0, stream,
                             rp, ecv, y, xpk);
        mode1();
        mode2(score);
      }
    }
  }

  hipLaunchKernelGGL(k_final, dim3(cdiv(NN, 256)), dim3(256), 0, stream, sc, b3, out);
}

// Round 7
// 4266.421 us; speedup vs baseline: 1.3321x; 1.3321x over previous
//
#include <hip/hip_runtime.h>
#include <hip/hip_fp16.h>

#define NN 100000
#define NE 1600000
#define HD 128
#define HD2 256

// binned scatter params
#define NBK 512
#define RPB 196      // rows per bucket; 512*196 = 100352 >= NN
#define CH  4096     // edges per binscatter block
#define CAP 4096     // staging capacity per bucket (17-sigma above mean 3136)

typedef unsigned int u32;
typedef unsigned short u16;
typedef _Float16 half8 __attribute__((ext_vector_type(8)));
typedef float floatx4 __attribute__((ext_vector_type(4)));

static inline int cdiv(int a, int b){ return (a + b - 1) / b; }

// ---- split-fp16 packing: x ~= h + l * 2^-12, l pre-scaled by 4096 ----
__device__ __forceinline__ u32 split_pack(float v){
  __half h;
  if(fabsf(v) < 6.103515625e-05f) h = __ushort_as_half((u16)0);
  else h = __float2half_rn(v);
  float hf = __half2float(h);
  __half l = __float2half_rn((v - hf) * 4096.0f);
  return (u32)__half_as_ushort(h) | ((u32)__half_as_ushort(l) << 16);
}

// ---------------- fused setup: all-weights split + score zero + bucket-cursor init ----
// weight dests are contiguous in workspace: 8x[128*128] + [128*256] + [256*256] u32.
__global__ void k_setup(const float* __restrict__ w0, const float* __restrict__ w1,
                        const float* __restrict__ w2, const float* __restrict__ w3,
                        const float* __restrict__ w4, const float* __restrict__ w5,
                        const float* __restrict__ w6, const float* __restrict__ w7,
                        const float* __restrict__ m1, const float* __restrict__ m2,
                        u32* __restrict__ wbase, float* __restrict__ sc,
                        int* __restrict__ bcur){
  int bid = blockIdx.x;
  if(bid < 896){
    int idx = bid * 256 + threadIdx.x;      // 896*256 = 229376 exact
    const float* W; int K, N, local;
    if(idx < 131072){
      int wi = idx >> 14; local = idx & 16383; K = HD; N = HD;
      W = wi == 0 ? w0 : wi == 1 ? w1 : wi == 2 ? w2 : wi == 3 ? w3 :
          wi == 4 ? w4 : wi == 5 ? w5 : wi == 6 ? w6 : w7;
    } else if(idx < 163840){
      local = idx - 131072; K = HD; N = HD2; W = m1;
    } else {
      local = idx - 163840; K = HD2; N = HD2; W = m2;
    }
    int n = local / K, k = local - n * K;
    wbase[idx] = split_pack(W[(size_t)k * N + n]);
  } else if(bid < 896 + 782){
    int i = (bid - 896) * 256 + threadIdx.x;
    if(i < 2 * NN) sc[i] = 0.f;
  } else {
    int i = (bid - 896 - 782) * 256 + threadIdx.x;
    if(i < 2 * NBK) bcur[i] = (i & (NBK - 1)) * CAP;
  }
}

// pass B: LDS-binned scatter into fixed-capacity bucket staging (burst writes)
__global__ void k_binscatter(const int* __restrict__ r0a, const int* __restrict__ c0a,
                             const float* __restrict__ v0a,
                             const int* __restrict__ r1a, const int* __restrict__ c1a,
                             const float* __restrict__ v1a,
                             int* __restrict__ bcur,
                             u32* __restrict__ sr0, uint2* __restrict__ sv0,
                             u32* __restrict__ sr1, uint2* __restrict__ sv1){
  __shared__ int cnt[NBK];
  __shared__ int bstart[NBK];
  __shared__ int gbase[NBK];
  __shared__ int sh[256];
  __shared__ u32 srow[CH];
  __shared__ uint2 scvs[CH];
  int z = blockIdx.y;
  const int* rows = z ? r1a : r0a;
  const int* cols = z ? c1a : c0a;
  const float* vals = z ? v1a : v0a;
  int* cur = bcur + z * NBK;
  u32* osr = z ? sr1 : sr0;
  uint2* osv = z ? sv1 : sv0;
  int t = threadIdx.x;
  for(int i = t; i < NBK; i += 256) cnt[i] = 0;
  __syncthreads();
  int e0 = blockIdx.x * CH;
  int total = NE - e0; if(total > CH) total = CH;
  int r_[16], c_[16], b_[16], k_[16]; float v_[16];
  #pragma unroll
  for(int k = 0; k < 16; k++){
    int e = e0 + t + k * 256;
    b_[k] = -1;
    if(e < NE){
      r_[k] = rows[e]; c_[k] = cols[e]; v_[k] = vals[e];
      b_[k] = r_[k] / RPB;
      k_[k] = atomicAdd(&cnt[b_[k]], 1);
    }
  }
  __syncthreads();
  // exclusive scan of cnt[512] with 256 threads (2 elems/thread)
  int v0 = cnt[2 * t], v1 = cnt[2 * t + 1];
  int s2 = v0 + v1;
  sh[t] = s2;
  __syncthreads();
  for(int d = 1; d < 256; d <<= 1){
    int tv = (t >= d) ? sh[t - d] : 0;
    __syncthreads();
    sh[t] += tv;
    __syncthreads();
  }
  int excl = sh[t] - s2;
  bstart[2 * t] = excl;
  bstart[2 * t + 1] = excl + v0;
  __syncthreads();
  // stage into LDS sorted-by-bucket
  #pragma unroll
  for(int k = 0; k < 16; k++){
    if(b_[k] >= 0){
      int slot = bstart[b_[k]] + k_[k];
      srow[slot] = (u32)r_[k];
      scvs[slot] = make_uint2((u32)c_[k], __float_as_uint(v_[k]));
    }
  }
  // reserve staging space per bucket (one atomic per non-empty bucket)
  for(int b = t; b < NBK; b += 256){
    int c = cnt[b];
    if(c > 0) gbase[b] = atomicAdd(&cur[b], c);
  }
  __syncthreads();
  // burst write-out: consecutive i -> same bucket -> contiguous dest
  for(int i = t; i < total; i += 256){
    u32 r = srow[i];
    int b = (int)r / RPB;
    int dest = gbase[b] + (i - bstart[b]);
    osr[dest] = r;
    osv[dest] = scvs[i];
  }
}

// bucket totals -> global bucket bases (exclusive scan over 512), + rowptr[NN]=NE
__global__ void k_bucket_scan(const int* __restrict__ bcur, int* __restrict__ bbase,
                              int* __restrict__ c1ptr, int* __restrict__ c2ptr){
  __shared__ int sh[256];
  int z = blockIdx.x;
  const int* cur = bcur + z * NBK;
  int* bb = bbase + z * NBK;
  int t = threadIdx.x;
  int v0 = cur[2 * t]     - (2 * t) * CAP;
  int v1 = cur[2 * t + 1] - (2 * t + 1) * CAP;
  int s2 = v0 + v1;
  sh[t] = s2;
  __syncthreads();
  for(int d = 1; d < 256; d <<= 1){
    int tv = (t >= d) ? sh[t - d] : 0;
    __syncthreads();
    sh[t] += tv;
    __syncthreads();
  }
  int excl = sh[t] - s2;
  bb[2 * t] = excl;
  bb[2 * t + 1] = excl + v0;
  if(t == 0){
    int* rp = z ? c2ptr : c1ptr;
    rp[NN] = NE;
  }
}

// pass C: per-bucket — LDS row-histogram + local scan -> rowptr, then CSR placement
__global__ void k_bucket_place(const int* __restrict__ bcur, const int* __restrict__ bbase,
                               const u32* __restrict__ sr0, const uint2* __restrict__ sv0,
                               const u32* __restrict__ sr1, const uint2* __restrict__ sv1,
                               int* __restrict__ c1ptr, int* __restrict__ c2ptr,
                               uint2* __restrict__ e0, uint2* __restrict__ e1){
  __shared__ int hist[RPB];
  __shared__ int cur[RPB];
  __shared__ int sh[256];
  __shared__ u32 srows[CAP];
  int z = blockIdx.y;
  int b = blockIdx.x;
  int r0 = b * RPB;
  if(r0 >= NN) return;
  int rend = r0 + RPB; if(rend > NN) rend = NN;
  int nr = rend - r0;
  const u32* sr = z ? sr1 : sr0;
  const uint2* sv = z ? sv1 : sv0;
  int* rp = z ? c2ptr : c1ptr;
  uint2* ecv = z ? e1 : e0;
  int cnt = bcur[z * NBK + b] - b * CAP;
  int base = bbase[z * NBK + b];
  int g = b * CAP;
  int t = threadIdx.x;
  for(int r = t; r < nr; r += 256) hist[r] = 0;
  __syncthreads();
  for(int i = t; i < cnt; i += 256){
    u32 r = sr[g + i];
    srows[i] = r;
    atomicAdd(&hist[(int)r - r0], 1);
  }
  __syncthreads();
  int v = (t < nr) ? hist[t] : 0;
  sh[t] = v;
  __syncthreads();
  for(int d = 1; d < 256; d <<= 1){
    int tv = (t >= d) ? sh[t - d] : 0;
    __syncthreads();
    sh[t] += tv;
    __syncthreads();
  }
  int excl = sh[t] - v;
  if(t < nr){
    rp[r0 + t] = base + excl;
    cur[t] = base + excl;
  }
  __syncthreads();
  for(int i = t; i < cnt; i += 256){
    int r = (int)srows[i] - r0;
    int p = atomicAdd(&cur[r], 1);
    ecv[p] = sv[g + i];
  }
}

// ---------------- SpMM: one wave per node; relu (+ optional l2norm); packed-split output ----
template<bool NORM>
__global__ void k_spmm(const int* __restrict__ rowptr, const uint2* __restrict__ ecv,
                       const float* __restrict__ X, u32* __restrict__ outpk){
  int node = (blockIdx.x << 2) + (threadIdx.x >> 6);
  int lane = threadIdx.x & 63;
  if(node >= NN) return;
  int s = rowptr[node], e = rowptr[node + 1];
  float ax = 0.f, ay = 0.f, bx = 0.f, by = 0.f;
  int i = s;
  for(; i + 15 < e; i += 16){
    uint2 ee[16]; float2 xx[16];
    #pragma unroll
    for(int j = 0; j < 16; j++) ee[j] = ecv[i + j];
    #pragma unroll
    for(int j = 0; j < 16; j++) xx[j] = *(const float2*)(X + (size_t)ee[j].x * HD + lane * 2);
    #pragma unroll
    for(int j = 0; j < 16; j += 4){
      ax += __uint_as_float(ee[j].y)   * xx[j].x   + __uint_as_float(ee[j+1].y) * xx[j+1].x;
      ay += __uint_as_float(ee[j].y)   * xx[j].y   + __uint_as_float(ee[j+1].y) * xx[j+1].y;
      bx += __uint_as_float(ee[j+2].y) * xx[j+2].x + __uint_as_float(ee[j+3].y) * xx[j+3].x;
      by += __uint_as_float(ee[j+2].y) * xx[j+2].y + __uint_as_float(ee[j+3].y) * xx[j+3].y;
    }
  }
  for(; i + 3 < e; i += 4){
    uint2 f0 = ecv[i], f1 = ecv[i+1], f2 = ecv[i+2], f3 = ecv[i+3];
    float2 x0 = *(const float2*)(X + (size_t)f0.x * HD + lane * 2);
    float2 x1 = *(const float2*)(X + (size_t)f1.x * HD + lane * 2);
    float2 x2 = *(const float2*)(X + (size_t)f2.x * HD + lane * 2);
    float2 x3 = *(const float2*)(X + (size_t)f3.x * HD + lane * 2);
    ax += __uint_as_float(f0.y) * x0.x + __uint_as_float(f1.y) * x1.x;
    ay += __uint_as_float(f0.y) * x0.y + __uint_as_float(f1.y) * x1.y;
    bx += __uint_as_float(f2.y) * x2.x + __uint_as_float(f3.y) * x3.x;
    by += __uint_as_float(f2.y) * x2.y + __uint_as_float(f3.y) * x3.y;
  }
  for(; i < e; i++){
    uint2 f0 = ecv[i];
    float2 xv = *(const float2*)(X + (size_t)f0.x * HD + lane * 2);
    ax += __uint_as_float(f0.y) * xv.x;
    ay += __uint_as_float(f0.y) * xv.y;
  }
  ax += bx; ay += by;
  ax = fmaxf(ax, 0.f);
  ay = fmaxf(ay, 0.f);
  if(NORM){
    float ss = ax * ax + ay * ay;
    #pragma unroll
    for(int o = 32; o >= 1; o >>= 1) ss += __shfl_xor(ss, o, 64);
    float scale = 1.f / fmaxf(sqrtf(ss), 1e-12f);
    ax *= scale; ay *= scale;
  }
  *(uint2*)(outpk + (size_t)node * HD + lane * 2) = make_uint2(split_pack(ax), split_pack(ay));
}

// ---------------- split-fp16 MFMA GEMM (round-6-proven body, XCD-paired col-tiles) ----
// 1-D grid. Block d -> (row-tile rt, col-tile ct) such that all NYC col-tiles of a
// row-panel land on the SAME XCD (d%8 equal), 8 dispatch slots apart -> the A panel
// is fetched from HBM once and L2-hit by the other col-tile(s).
// A: packed [M][K]; Bt: packed [N][K] (pre-transposed).
// MODE 0: Yout = A@B (fp32). MODE 1: Hout = pack(relu(A@B+bias)).
// MODE 2: score[m] += sum_n relu(A@B+bias)[m][n]*m3[n].
// MODE 3: fused — ct==0: mode0 with Bt0 -> Yout [M][HD];
//                 ct in {1,2}: mode1 col-tile with Bt1 -> Hout [M][HD2].
template<int MODE>
__launch_bounds__(256, 2)
__global__ void k_mfma_gemm(const u32* __restrict__ Apk, const u32* __restrict__ Btpk,
                            const u32* __restrict__ Bt1pk,
                            const float* __restrict__ bias, float* __restrict__ Yout,
                            u32* __restrict__ Hout, const float* __restrict__ m3,
                            float* __restrict__ score, int M, int K, int N){
  __shared__ u16 As_h[128 * 40], As_l[128 * 40];
  __shared__ u16 Bs_h[128 * 40], Bs_l[128 * 40];
  constexpr int NYC = (MODE == 0) ? 1 : ((MODE == 3) ? 3 : 2);
  const int d = blockIdx.x;
  const int grp = d / (8 * NYC);
  const int rem = d - grp * 8 * NYC;
  const int rt = grp * 8 + (rem & 7);
  const int ct = rem >> 3;
  const int nrt = (M + 127) >> 7;
  if(rt >= nrt) return;
  const int tid = threadIdx.x;
  const int lane = tid & 63, wid = tid >> 6;
  const int lm = lane & 15, lg = lane >> 4;
  const int mq = (wid & 1) * 64, nq = (wid >> 1) * 64;
  const int m0 = rt * 128;
  int n0 = ct * 128;
  const u32* Bt = Btpk;
  bool m0path = true;
  if(MODE == 3){
    m0path = (ct == 0);
    if(m0path){ n0 = 0; }
    else      { n0 = (ct - 1) * 128; Bt = Bt1pk; }
  }

  floatx4 accA[4][4], accB[4][4];
  #pragma unroll
  for(int i = 0; i < 4; i++)
    #pragma unroll
    for(int j = 0; j < 4; j++){
      accA[i][j] = (floatx4){0.f, 0.f, 0.f, 0.f};
      accB[i][j] = (floatx4){0.f, 0.f, 0.f, 0.f};
    }

  for(int k0 = 0; k0 < K; k0 += 32){
    uint4 av[4], bv[4];
    #pragma unroll
    for(int j = 0; j < 4; j++){
      int li = tid + j * 256;
      int row = li >> 3, kc = (li & 7) * 4;
      int ar = m0 + row; if(ar >= M) ar = M - 1;
      av[j] = *(const uint4*)(Apk + (size_t)ar * K + k0 + kc);
      bv[j] = *(const uint4*)(Bt + (size_t)(n0 + row) * K + k0 + kc);
    }
    if(k0) __syncthreads();
    #pragma unroll
    for(int j = 0; j < 4; j++){
      int li = tid + j * 256;
      int row = li >> 3, kc = (li & 7) * 4;
      int base = row * 40 + kc;
      ushort4 h, l;
      h.x = (u16)(av[j].x & 0xffff); l.x = (u16)(av[j].x >> 16);
      h.y = (u16)(av[j].y & 0xffff); l.y = (u16)(av[j].y >> 16);
      h.z = (u16)(av[j].z & 0xffff); l.z = (u16)(av[j].z >> 16);
      h.w = (u16)(av[j].w & 0xffff); l.w = (u16)(av[j].w >> 16);
      *(ushort4*)&As_h[base] = h;
      *(ushort4*)&As_l[base] = l;
      h.x = (u16)(bv[j].x & 0xffff); l.x = (u16)(bv[j].x >> 16);
      h.y = (u16)(bv[j].y & 0xffff); l.y = (u16)(bv[j].y >> 16);
      h.z = (u16)(bv[j].z & 0xffff); l.z = (u16)(bv[j].z >> 16);
      h.w = (u16)(bv[j].w & 0xffff); l.w = (u16)(bv[j].w >> 16);
      *(ushort4*)&Bs_h[base] = h;
      *(ushort4*)&Bs_l[base] = l;
    }
    __syncthreads();

    half8 fa_h[4], fa_l[4], fb_h[4], fb_l[4];
    #pragma unroll
    for(int s = 0; s < 4; s++){
      int ra = (mq + s * 16 + lm) * 40 + lg * 8;
      fa_h[s] = *(const half8*)&As_h[ra];
      fa_l[s] = *(const half8*)&As_l[ra];
      int rb = (nq + s * 16 + lm) * 40 + lg * 8;
      fb_h[s] = *(const half8*)&Bs_h[rb];
      fb_l[s] = *(const half8*)&Bs_l[rb];
    }
    #pragma unroll
    for(int i = 0; i < 4; i++)
      #pragma unroll
      for(int j = 0; j < 4; j++){
        accA[i][j] = __builtin_amdgcn_mfma_f32_16x16x32_f16(fa_h[i], fb_h[j], accA[i][j], 0, 0, 0);
        accB[i][j] = __builtin_amdgcn_mfma_f32_16x16x32_f16(fa_h[i], fb_l[j], accB[i][j], 0, 0, 0);
        accB[i][j] = __builtin_amdgcn_mfma_f32_16x16x32_f16(fa_l[i], fb_h[j], accB[i][j], 0, 0, 0);
      }
  }

  const float inv4096 = 1.f / 4096.f;
  if(MODE == 0 || (MODE == 3 && m0path)){
    int ldy = (MODE == 3) ? HD : N;
    #pragma unroll
    for(int i = 0; i < 4; i++)
      #pragma unroll
      for(int r = 0; r < 4; r++){
        int m = m0 + mq + i * 16 + lg * 4 + r;
        if(m < M){
          #pragma unroll
          for(int j = 0; j < 4; j++){
            int c = n0 + nq + j * 16 + lm;
            Yout[(size_t)m * ldy + c] = accA[i][j][r] + accB[i][j][r] * inv4096;
          }
        }
      }
  } else if(MODE == 1 || MODE == 3){
    int ldh = (MODE == 3) ? HD2 : N;
    #pragma unroll
    for(int i = 0; i < 4; i++)
      #pragma unroll
      for(int r = 0; r < 4; r++){
        int m = m0 + mq + i * 16 + lg * 4 + r;
        if(m < M){
          #pragma unroll
          for(int j = 0; j < 4; j++){
            int c = n0 + nq + j * 16 + lm;
            float v = fmaxf(accA[i][j][r] + accB[i][j][r] * inv4096 + bias[c], 0.f);
            Hout[(size_t)m * ldh + c] = split_pack(v);
          }
        }
      }
  } else {
    #pragma unroll
    for(int i = 0; i < 4; i++)
      #pragma unroll
      for(int r = 0; r < 4; r++){
        float s = 0.f;
        #pragma unroll
        for(int j = 0; j < 4; j++){
          int c = n0 + nq + j * 16 + lm;
          float v = fmaxf(accA[i][j][r] + accB[i][j][r] * inv4096 + bias[c], 0.f);
          s = fmaf(v, m3[c], s);
        }
        s += __shfl_xor(s, 1, 64);
        s += __shfl_xor(s, 2, 64);
        s += __shfl_xor(s, 4, 64);
        s += __shfl_xor(s, 8, 64);
        int m = m0 + mq + i * 16 + lg * 4 + r;
        if(lm == 0 && m < M) atomicAdd(&score[m], s);
      }
  }
}

__global__ void k_final(const float* __restrict__ sc, const float* __restrict__ b3,
                        float* __restrict__ out){
  int i = blockIdx.x * 256 + threadIdx.x;
  if(i < NN){
    float b = 9.f * b3[0];
    out[i] = (sc[i] + b) * (sc[NN + i] + b);
  }
}

// ---------------- launcher ----------------
extern "C" void kernel_launch(void* const* d_in, const int* in_sizes, int n_in,
                              void* d_out, int out_size, void* d_ws, size_t ws_size,
                              hipStream_t stream){
  const int*   a1r = (const int*)d_in[0];
  const int*   a1c = (const int*)d_in[1];
  const float* a1v = (const float*)d_in[2];
  const int*   a2r = (const int*)d_in[3];
  const int*   a2c = (const int*)d_in[4];
  const float* a2v = (const float*)d_in[5];
  const float* w1  = (const float*)d_in[6];
  const float* w[8];
  for(int i = 0; i < 8; i++) w[i] = (const float*)d_in[7 + i];
  const float* m1 = (const float*)d_in[15];
  const float* b1 = (const float*)d_in[16];
  const float* m2 = (const float*)d_in[17];
  const float* b2 = (const float*)d_in[18];
  const float* m3 = (const float*)d_in[19];
  const float* b3 = (const float*)d_in[20];
  float* out = (float*)d_out;

  char* base = (char*)d_ws;
  size_t off = 0;
  auto alloc = [&](size_t bytes) -> char* {
    char* r = base + off;
    off += (bytes + 255) & ~(size_t)255;
    return r;
  };
  int*   c1ptr = (int*)  alloc((size_t)(NN + 1) * 4);
  int*   c2ptr = (int*)  alloc((size_t)(NN + 1) * 4);
  uint2* ecv1  = (uint2*)alloc((size_t)NE * 8);
  uint2* ecv2  = (uint2*)alloc((size_t)NE * 8);
  int*   cursor= (int*)  alloc((size_t)2 * NBK * 4);
  int*   bbase = (int*)  alloc((size_t)2 * NBK * 4);
  float* sc    = (float*)alloc((size_t)2 * NN * 4);
  u32*   wtpk[8];
  for(int i = 0; i < 8; i++) wtpk[i] = (u32*)alloc((size_t)HD * HD * 4);
  u32*   m1tpk = (u32*)alloc((size_t)HD2 * HD * 4);
  u32*   m2tpk = (u32*)alloc((size_t)HD2 * HD2 * 4);
  u32*   xpk   = (u32*)alloc((size_t)NN * HD * 4);
  u32*   h1pk  = (u32*)alloc((size_t)NN * HD2 * 4);
  // fused01 tier needs dedicated y (fp32 [NN][HD]); else alias h1pk and run r6 schedule
  size_t need_ded = off + (((size_t)NN * HD * 4 + 255) & ~(size_t)255);
  bool ded_y = (ws_size >= need_ded);
  float* y = ded_y ? (float*)alloc((size_t)NN * HD * 4) : (float*)h1pk;

  // binned-scatter staging aliases h1pk (dead during CSR build): 50.3MB < 102.4MB
  const size_t SZ = (size_t)NBK * CAP;
  char* hb = (char*)h1pk;
  uint2* sv1 = (uint2*)hb;
  u32*   sr1 = (u32*)(hb + SZ * 8);
  uint2* sv2 = (uint2*)(hb + SZ * 12);
  u32*   sr2 = (u32*)(hb + SZ * 20);

  // ---- fused setup (weight split + sc zero + bucket cursor init), then CSR build ----
  hipLaunchKernelGGL(k_setup, dim3(896 + 782 + 4), dim3(256), 0, stream,
                     w[0], w[1], w[2], w[3], w[4], w[5], w[6], w[7], m1, m2,
                     wtpk[0], sc, cursor);
  hipLaunchKernelGGL(k_binscatter, dim3(cdiv(NE, CH), 2), dim3(256), 0, stream,
                     a1r, a1c, a1v, a2r, a2c, a2v, cursor, sr1, sv1, sr2, sv2);
  hipLaunchKernelGGL(k_bucket_scan, dim3(2), dim3(256), 0, stream, cursor, bbase, c1ptr, c2ptr);
  hipLaunchKernelGGL(k_bucket_place, dim3(NBK, 2), dim3(256), 0, stream,
                     cursor, bbase, sr1, sv1, sr2, sv2, c1ptr, c2ptr, ecv1, ecv2);

  const int NRT = cdiv(NN, 128);          // 782 row tiles
  const int GP  = cdiv(NRT, 8) * 8;       // 784 padded rows
  const int SPB = cdiv(NN, 4);            // 25000 spmm blocks
  auto mode1 = [&](){
    hipLaunchKernelGGL((k_mfma_gemm<1>), dim3(GP * 2), dim3(256), 0, stream,
                       xpk, m1tpk, (const u32*)nullptr, b1, (float*)nullptr, h1pk,
                       (const float*)nullptr, (float*)nullptr, NN, HD, HD2);
  };
  auto mode2 = [&](float* score){
    hipLaunchKernelGGL((k_mfma_gemm<2>), dim3(GP * 2), dim3(256), 0, stream,
                       h1pk, m2tpk, (const u32*)nullptr, b2, (float*)nullptr, (u32*)nullptr,
                       m3, score, NN, HD2, HD2);
  };
  auto gemm0 = [&](int i){
    hipLaunchKernelGGL((k_mfma_gemm<0>), dim3(GP * 1), dim3(256), 0, stream,
                       xpk, wtpk[i], (const u32*)nullptr, (const float*)nullptr, y, (u32*)nullptr,
                       (const float*)nullptr, (float*)nullptr, NN, HD, HD);
  };
  auto fused01 = [&](int i){
    hipLaunchKernelGGL((k_mfma_gemm<3>), dim3(GP * 3), dim3(256), 0, stream,
                       xpk, wtpk[i], m1tpk, b1, y, h1pk,
                       (const float*)nullptr, (float*)nullptr, NN, HD, 0);
  };

  for(int b = 0; b < 2; b++){
    const int* rp = b ? c2ptr : c1ptr;
    const uint2* ecv = b ? ecv2 : ecv1;
    float* score = sc + (size_t)b * NN;
    hipLaunchKernelGGL((k_spmm<true>), dim3(SPB), dim3(256), 0, stream,
                       rp, ecv, w1, xpk);
    if(ded_y){
      // spmm; 8x [fused01(h1,y); mode2; spmm]; mode1; mode2
      for(int i = 0; i < 8; i++){
        fused01(i);
        mode2(score);
        if(i < 7)
          hipLaunchKernelGGL((k_spmm<true>),  dim3(SPB), dim3(256), 0, stream,
                             rp, ecv, y, xpk);
        else
          hipLaunchKernelGGL((k_spmm<false>), dim3(SPB), dim3(256), 0, stream,
                             rp, ecv, y, xpk);
      }
      mode1();
      mode2(score);
    } else {
      // r6-proven serial order (y aliases h1pk)
      mode1();
      mode2(score);
      for(int i = 0; i < 8; i++){
        gemm0(i);
        if(i < 7)
          hipLaunchKernelGGL((k_spmm<true>),  dim3(SPB), dim3(256), 0, stream,
                             rp, ecv, y, xpk);
        else
          hipLaunchKernelGGL((k_spmm<false>), dim3(SPB), dim3(256), 0, stream,
                             rp, ecv, y, xpk);
        mode1();
        mode2(score);
      }
    }
  }

  hipLaunchKernelGGL(k_final, dim3(cdiv(NN, 256)), dim3(256), 0, stream, sc, b3, out);
}